// Round 1
// baseline (138.747 us; speedup 1.0000x reference)
//
#include <hip/hip_runtime.h>
#include <cstdint>

// DetNet NMS, round 19. r18 accounting: k2+k_mask+k3 ~= 95-100us vs 138us
// measured => ~40us of launch/boundary overhead + k_mask fully exposed.
// r19: FUSE k_mask+k3 into one 128-block launch:
//   block 0     = serial NMS consumer (identical decision math to r18; drops
//                 the 98KB sband LDS staging, prefetches the 4-word band for
//                 chunk T+1 from global while scanning chunk T, gated on
//                 done[T+1] counters).
//   blocks 1..127 = mask builders: same 64-IoU/thread LDS-staged tiles as
//                 k_mask (64 rows x 8 words per tile), enumerated globally
//                 CHUNK-MAJOR and strided over 127 blocks so chunk 0 is
//                 built first (~16 tiles in parallel, ready in ~1-2us).
//                 Per-tile publish: agent-scope RELEASE atomicAdd on done[c]
//                 (+ __threadfence) => cross-XCD L2 writeback before the
//                 consumer's acquire. Builders never spin => deadlock-free
//                 without cooperative launch.
// k2 unchanged except zeroing done[64] (ws is poisoned each iter).
// All decision-critical FP math __f*_rn in exact ref op order (absmax 0.0
// r1-4, 6-9, 11-15, 17-18).

#define M_TOT 8192
#define NMS_T 0.3f

// ws layout (bytes)
#define WS_BOX   65536      // float4[8192]
#define WS_D     196608     // float[40960]
#define WS_VCNT  360448     // u32
#define WS_ZROW  393216     // u64[128] dummy zero row (zeroed by k2)
#define WS_DONE  458752     // u32[64] per-chunk build counters (zeroed by k2)
#define WS_MASK  524288     // u64[8192*128] = 8 MB

typedef unsigned long long u64t;

__device__ __forceinline__ uint32_t desc_key(float sv) {
    uint32_t u = __float_as_uint(sv);
    uint32_t m = (u & 0x80000000u) ? ~u : (u | 0x80000000u);
    return ~m;
}
__device__ __forceinline__ u64t rdl64(u64t v, int sl) {
    unsigned lo = (unsigned)__builtin_amdgcn_readlane((int)(unsigned)v, sl);
    unsigned hi = (unsigned)__builtin_amdgcn_readlane((int)(unsigned)(v >> 32), sl);
    return ((u64t)hi << 32) | lo;
}
__device__ __forceinline__ u64t rdfl64(u64t v) {
    unsigned lo = (unsigned)__builtin_amdgcn_readfirstlane((int)(unsigned)v);
    unsigned hi = (unsigned)__builtin_amdgcn_readfirstlane((int)(unsigned)(v >> 32));
    return ((u64t)hi << 32) | lo;
}

__device__ __forceinline__ void scatter_one(
    int i, int rank, u64t key,
    const float* __restrict__ det, const float* __restrict__ offsets,
    const float* __restrict__ scales,
    float4* __restrict__ boxes_srt, float* __restrict__ d_srt)
{
    uint32_t dkey = (uint32_t)(key >> 16);
    if (dkey >= 0x7FFFFFFFu) return;     // score <= 0: row stays zero
    int g = i >> 10;
    float d0 = __fadd_rn(offsets[g*5+0], __fmul_rn(det[i*5+0], scales[g*5+0]));
    float d1 = __fadd_rn(offsets[g*5+1], __fmul_rn(det[i*5+1], scales[g*5+1]));
    float d2 = __fadd_rn(offsets[g*5+2], __fmul_rn(det[i*5+2], scales[g*5+2]));
    float d3 = __fadd_rn(offsets[g*5+3], __fmul_rn(det[i*5+3], scales[g*5+3]));
    float d4 = __fadd_rn(offsets[g*5+4], __fmul_rn(det[i*5+4], scales[g*5+4]));
    d_srt[rank*5+0] = d0; d_srt[rank*5+1] = d1; d_srt[rank*5+2] = d2;
    d_srt[rank*5+3] = d3; d_srt[rank*5+4] = d4;
    float hw = __fmul_rn(d3, 0.5f), hh = __fmul_rn(d4, 0.5f);
    boxes_srt[rank] = make_float4(__fsub_rn(d1, hw), __fsub_rn(d2, hh),
                                  __fadd_rn(d1, hw), __fadd_rn(d2, hh));
}

// 128 blocks x 512 threads: 8 waves/block = 2/SIMD on active CUs
__global__ __launch_bounds__(512) void k2_rank(
    const float* __restrict__ det, const float* __restrict__ offsets,
    const float* __restrict__ scales, const float* __restrict__ bounds,
    float4* __restrict__ boxes_srt, float* __restrict__ d_srt,
    unsigned int* __restrict__ vcnt, u64t* __restrict__ zrow,
    unsigned int* __restrict__ done, float* __restrict__ out)
{
    __shared__ u64t skey[M_TOT];
    __shared__ float soff[40], sscl[40], sbnd[32];
    __shared__ int sTop;
    int t = threadIdx.x;
    int lane = t & 63;
    if (t == 0) sTop = 0;
    if (t < 40) { soff[t] = offsets[t]; sscl[t] = scales[t]; }
    if (t < 32) { sbnd[t] = bounds[t]; }
    if (blockIdx.x == 0 && t < 128) zrow[t] = 0ull;
    if (blockIdx.x == 0 && t < 64)  done[t] = 0u;
    __syncthreads();

    #pragma unroll 4
    for (int s = 0; s < 16; ++s) {
        int u = s * 512 + t;
        int g = u >> 10;
        float raw_s = det[u * 5 + 0];
        float cx    = det[u * 5 + 1];
        float cy    = det[u * 5 + 2];
        float score = __fadd_rn(soff[g * 5 + 0], __fmul_rn(raw_s, sscl[g * 5 + 0]));
        bool valid = (cx < sbnd[g*4+1]) && (cx > sbnd[g*4+0]) &&
                     (cy < sbnd[g*4+3]) && (cy > sbnd[g*4+2]);
        float sv = valid ? score : -1.0f;
        uint32_t dk = desc_key(sv);
        bool push = dk < 0x7FFFFFFFu;
        u64t key = ((u64t)dk << 16) | (unsigned)u;
        u64t bal = __ballot(push);
        if (bal) {
            int lw = 0;
            if (lane == 0) lw = atomicAdd(&sTop, __popcll(bal));
            int wbase = __builtin_amdgcn_readfirstlane(lw);
            if (push) {
                int off = __popcll(bal & ((1ull << lane) - 1ull));
                skey[wbase + off] = key;
            }
        }
    }
    __syncthreads();
    int V = sTop;
    int Vpad = (V + 15) & ~15;
    if (t < Vpad - V) skey[V + t] = ~0ull;
    {
        int zb = blockIdx.x * 320;       // 128 blocks x 320 = 40960
        for (int z = zb + t; z < zb + 320; z += 512) out[z] = 0.0f;
    }
    __syncthreads();
    if (t == 0) *vcnt = (unsigned)V;

    int grp = t >> 3;                    // 0..63
    int jq  = t & 7;
    int i = blockIdx.x * 64 + grp;       // 128*64 = 8192
    int g = i >> 10;
    float raw_s = det[i * 5 + 0];
    float cx    = det[i * 5 + 1];
    float cy    = det[i * 5 + 2];
    float score = __fadd_rn(soff[g * 5 + 0], __fmul_rn(raw_s, sscl[g * 5 + 0]));
    bool valid = (cx < sbnd[g*4+1]) && (cx > sbnd[g*4+0]) &&
                 (cy < sbnd[g*4+3]) && (cy > sbnd[g*4+2]);
    float sv = valid ? score : -1.0f;
    uint32_t dk = desc_key(sv);
    u64t ki = ((u64t)dk << 16) | (unsigned)i;
    const ulonglong2* skey2 = (const ulonglong2*)skey;
    int c = 0;
    int nit = Vpad >> 4;
    #pragma unroll 4
    for (int it = 0; it < nit; ++it) {
        ulonglong2 kj = skey2[it * 8 + jq];
        c += (kj.x < ki) + (kj.y < ki);
    }
    c += __shfl_xor(c, 1);
    c += __shfl_xor(c, 2);
    c += __shfl_xor(c, 4);
    if (jq == 0)
        scatter_one(i, c, ki, det, offsets, scales, boxes_srt, d_srt);
}

// ---- fused mask-build + serial NMS ----
// block 0: consumer (serial wave + 7 helper waves, as r18 k3 minus sband).
// blocks 1..127: builders, chunk-major global tile enumeration.
__global__ __launch_bounds__(512) void k34_fused(
    const float4* __restrict__ boxes_srt,
    const u64t* __restrict__ zrow,
    const float* __restrict__ d_srt,
    const unsigned int* __restrict__ vcnt,
    u64t* __restrict__ mask,
    unsigned int* __restrict__ done,
    float* __restrict__ out)
{
    int V = (int)*vcnt;
    int nwords = (V + 63) >> 6;
    int nc = (V + 127) >> 7;             // 128-wide chunks
    int tid = threadIdx.x;

    if (blockIdx.x != 0) {
        // ---------------- builders ----------------
        __shared__ float4 sb[8 * 65];
        __shared__ float  sa[8 * 65];
        int b = (int)blockIdx.x - 1;     // 0..126
        int gpre = 0;                    // global tile prefix
        for (int c = 0; c < nc; ++c) {
            int w0 = 2 * c;
            int Wc = nwords - w0;                  // >= 1 for c < nc
            int tiles = 2 * ((Wc + 7) >> 3);       // 2 row-halves x word-octets
            int tau0 = ((b - gpre) % 127 + 127) % 127;
            for (int tau = tau0; tau < tiles; tau += 127) {
                int rt = tau & 1, wt = tau >> 1;
                int rowbase = c * 128 + rt * 64;
                int wbase = w0 + wt * 8;
                // stage 8 column groups (512 boxes) coalesced
                {
                    int u = tid;
                    float4 bb = boxes_srt[min(wbase * 64 + u, M_TOT - 1)];
                    int cc = u >> 6, jj = u & 63;
                    sb[cc * 65 + jj] = bb;
                    sa[cc * 65 + jj] = __fmul_rn(fmaxf(__fsub_rn(bb.z, bb.x), 0.0f),
                                                 fmaxf(__fsub_rn(bb.w, bb.y), 0.0f));
                }
                __syncthreads();
                int r  = rowbase + (tid >> 3);
                int wl = tid & 7;
                int w  = wbase + wl;
                if (r < V && w < nwords) {
                    float4 bi = boxes_srt[r];
                    float ai = __fmul_rn(fmaxf(__fsub_rn(bi.z, bi.x), 0.0f),
                                         fmaxf(__fsub_rn(bi.w, bi.y), 0.0f));
                    u64t bits = 0;
                    #pragma unroll 4
                    for (int jj = 0; jj < 64; ++jj) {
                        float4 bj = sb[wl * 65 + jj];
                        float aj = sa[wl * 65 + jj];
                        float iw = fmaxf(__fsub_rn(fminf(bi.z, bj.z), fmaxf(bi.x, bj.x)), 0.0f);
                        float ih = fmaxf(__fsub_rn(fminf(bi.w, bj.w), fmaxf(bi.y, bj.y)), 0.0f);
                        float inter = __fmul_rn(iw, ih);
                        float uni   = __fsub_rn(__fadd_rn(ai, aj), inter);
                        float iou   = __fdiv_rn(inter, fmaxf(uni, 1e-9f));
                        int j = w * 64 + jj;
                        if (j > r && iou > NMS_T) bits |= 1ull << jj;
                    }
                    mask[(size_t)r * 128 + w] = bits;
                }
                __syncthreads();         // all tile writes retired (vmcnt drain)
                if (tid == 0) {
                    int rows_t  = V - rowbase; if (rows_t > 64) rows_t = 64;
                    int words_t = nwords - wbase; if (words_t > 8) words_t = 8;
                    if (rows_t > 0) {
                        __threadfence();             // L2 writeback (agent)
                        __hip_atomic_fetch_add(&done[c], (unsigned)(rows_t * words_t),
                                               __ATOMIC_RELEASE, __HIP_MEMORY_SCOPE_AGENT);
                    }
                }
                __syncthreads();         // protect sb before next stage
            }
            gpre += tiles;
        }
        return;
    }

    // ---------------- block 0: consumer ----------------
    __shared__ u64t sdead[128];
    __shared__ u64t ck[128];                 // keptmask per 64-word
    __shared__ int  res_prog;
    __shared__ int  h_prog[7];
    int wv = tid >> 6, lane = tid & 63;

    if (tid < 128) {
        int bw = tid * 64;
        u64t w0v = 0;
        if (bw >= V)           w0v = ~0ull;
        else if (bw + 64 > V)  w0v = (~0ull) << (V - bw);
        sdead[tid] = w0v;
        ck[tid] = 0ull;
    }
    if (tid == 0) res_prog = 0;
    if (tid < 7)  h_prog[tid] = tid;
    __syncthreads();

    if (wv == 0) {
        if (nc > 0) {
            u64t cA_lo = 0, cA_hi = 0;
            // wait chunk 0 built, load its band
            {
                int rows_c = V; if (rows_c > 128) rows_c = 128;
                unsigned expc = (unsigned)(rows_c * nwords);
                while (__hip_atomic_load(&done[0], __ATOMIC_RELAXED, __HIP_MEMORY_SCOPE_AGENT) < expc)
                    __builtin_amdgcn_s_sleep(2);
                (void)__hip_atomic_load(&done[0], __ATOMIC_ACQUIRE, __HIP_MEMORY_SCOPE_AGENT);
            }
            ulonglong2 bl, bln, bh, bhn;
            {
                int rl = min(lane,      M_TOT - 1);
                int rh = min(64 + lane, M_TOT - 1);
                const u64t* rpl = mask + (size_t)rl * 128;
                const u64t* rph = mask + (size_t)rh * 128;
                bl  = *(const ulonglong2*)(rpl);
                bln = *(const ulonglong2*)(rpl + 2);
                bh  = *(const ulonglong2*)(rph);
                bhn = *(const ulonglong2*)(rph + 2);
            }
            for (int T = 0; T < nc; ++T) {
                ulonglong2 nbl, nbln, nbh, nbhn;
                bool havenext = (T + 1 < nc);
                if (havenext) {
                    int c = T + 1;
                    int rows_c = V - c * 128; if (rows_c > 128) rows_c = 128;
                    unsigned expc = (unsigned)(rows_c * (nwords - 2 * c));
                    while (__hip_atomic_load(&done[c], __ATOMIC_RELAXED, __HIP_MEMORY_SCOPE_AGENT) < expc)
                        __builtin_amdgcn_s_sleep(2);
                    (void)__hip_atomic_load(&done[c], __ATOMIC_ACQUIRE, __HIP_MEMORY_SCOPE_AGENT);
                    int rl = min(c * 128 + lane,      M_TOT - 1);
                    int rh = min(c * 128 + 64 + lane, M_TOT - 1);
                    int w = min(2 * c, 124);
                    const u64t* rpl = mask + (size_t)rl * 128;
                    const u64t* rph = mask + (size_t)rh * 128;
                    nbl  = *(const ulonglong2*)(rpl + w);
                    nbln = *(const ulonglong2*)(rpl + w + 2);
                    nbh  = *(const ulonglong2*)(rph + w);
                    nbhn = *(const ulonglong2*)(rph + w + 2);
                }
                if (T >= 2) {
                    int need = T - 1;
                    while (true) {
                        int hp = (lane < 7) ? ((volatile int*)h_prog)[lane] : 0x7FFFFFFF;
                        if (__ballot(hp < need) == 0ull) break;
                    }
                }
                u64t dlo = rdfl64(((volatile u64t*)sdead)[2 * T]);
                u64t dhi = rdfl64(((volatile u64t*)sdead)[2 * T + 1]);
                u64t live_lo = ~(dlo | cA_lo);
                u64t live_hi = ~(dhi | cA_hi);
                int rem = V - T * 128;
                if (rem < 128) {
                    live_lo &= (rem >= 64) ? ~0ull : ((rem <= 0) ? 0ull : ((1ull << rem) - 1ull));
                    int rh = rem - 64;
                    live_hi &= (rh >= 64) ? ~0ull : ((rh <= 0) ? 0ull : ((1ull << rh) - 1ull));
                }
                u64t km_lo = 0, km_hi = 0;
                while (live_lo) {
                    int bs = (int)__builtin_ctzll(live_lo);
                    km_lo |= 1ull << bs;
                    u64t rml = rdl64(bl.x, bs);
                    u64t rmh = rdl64(bl.y, bs);
                    live_lo &= ~rml & ~(1ull << bs);
                    live_hi &= ~rmh;
                }
                while (live_hi) {
                    int bs = (int)__builtin_ctzll(live_hi);
                    km_hi |= 1ull << bs;
                    u64t rmh = rdl64(bh.y, bs);   // bh.x zero/garbage-safe: live_lo==0
                    live_hi &= ~rmh & ~(1ull << bs);
                }
                if (lane == 0) { ck[2 * T] = km_lo; ck[2 * T + 1] = km_hi; }
                __threadfence_block();
                if (lane == 0) *(volatile int*)&res_prog = T + 1;
                u64t c1l = 0, c1h = 0, km = km_lo;
                while (km) {
                    int b_ = (int)__builtin_ctzll(km); km &= km - 1;
                    c1l |= rdl64(bln.x, b_); c1h |= rdl64(bln.y, b_);
                }
                km = km_hi;
                while (km) {
                    int b_ = (int)__builtin_ctzll(km); km &= km - 1;
                    c1l |= rdl64(bhn.x, b_); c1h |= rdl64(bhn.y, b_);
                }
                cA_lo = c1l; cA_hi = c1h;
                if (havenext) { bl = nbl; bln = nbln; bh = nbh; bhn = nbhn; }
            }
        }
    } else {
        int hh = wv - 1;
        for (int c = hh; c < nc; c += 7) {
            while (*(volatile int*)&res_prog <= c) __builtin_amdgcn_s_sleep(1);
            (void)__hip_atomic_load(&done[c], __ATOMIC_ACQUIRE, __HIP_MEMORY_SCOPE_AGENT);
            u64t kl = ((volatile u64t*)ck)[2 * c];
            u64t kh = ((volatile u64t*)ck)[2 * c + 1];
            if (kl | kh) {
                int base = c * 128;
                u64t ax = 0, ay = 0;
                while (kl | kh) {
                    ulonglong2 bq[4];
                    #pragma unroll
                    for (int q = 0; q < 4; ++q) {
                        const ulonglong2* ptr;
                        if (kl) {
                            int b_ = __builtin_ctzll(kl); kl &= kl - 1;
                            ptr = (const ulonglong2*)(mask + (size_t)(base + b_) * 128) + lane;
                        } else if (kh) {
                            int b_ = __builtin_ctzll(kh); kh &= kh - 1;
                            ptr = (const ulonglong2*)(mask + (size_t)(base + 64 + b_) * 128) + lane;
                        } else {
                            ptr = (const ulonglong2*)zrow + lane;
                        }
                        bq[q] = *ptr;
                    }
                    ax |= bq[0].x | bq[1].x | bq[2].x | bq[3].x;
                    ay |= bq[0].y | bq[1].y | bq[2].y | bq[3].y;
                }
                atomicOr(&sdead[2 * lane],     ax);
                atomicOr(&sdead[2 * lane + 1], ay);
            }
            __threadfence_block();
            if (lane == 0) ((volatile int*)h_prog)[hh] = c + 7;
        }
        if (lane == 0) ((volatile int*)h_prog)[hh] = 0x7FFFFFFF;
    }
    __syncthreads();
    if (tid < 128) {
        u64t m = ck[tid];
        while (m) {
            int b_ = __builtin_ctzll(m); m &= m - 1;
            int rr = tid * 64 + b_;
            out[rr * 5 + 0] = d_srt[rr * 5 + 0];
            out[rr * 5 + 1] = d_srt[rr * 5 + 1];
            out[rr * 5 + 2] = d_srt[rr * 5 + 2];
            out[rr * 5 + 3] = d_srt[rr * 5 + 3];
            out[rr * 5 + 4] = d_srt[rr * 5 + 4];
        }
    }
}

extern "C" void kernel_launch(void* const* d_in, const int* in_sizes, int n_in,
                              void* d_out, int out_size, void* d_ws, size_t ws_size,
                              hipStream_t stream) {
    const float* det     = (const float*)d_in[0];
    const float* offsets = (const float*)d_in[1];
    const float* scales  = (const float*)d_in[2];
    const float* bounds  = (const float*)d_in[3];
    float* out = (float*)d_out;
    char* ws = (char*)d_ws;
    float4*       boxes = (float4*)(ws + WS_BOX);
    float*        d_srt = (float*)(ws + WS_D);
    unsigned int* vcnt  = (unsigned int*)(ws + WS_VCNT);
    u64t*         zrow  = (u64t*)(ws + WS_ZROW);
    unsigned int* done  = (unsigned int*)(ws + WS_DONE);
    u64t*         mask  = (u64t*)(ws + WS_MASK);

    k2_rank<<<128, 512, 0, stream>>>(det, offsets, scales, bounds, boxes, d_srt, vcnt, zrow, done, out);
    k34_fused<<<128, 512, 0, stream>>>(boxes, zrow, d_srt, vcnt, mask, done, out);
}